// Round 3
// baseline (581.560 us; speedup 1.0000x reference)
//
#include <hip/hip_runtime.h>
#include <hip/hip_bf16.h>
#include <stdint.h>

typedef __bf16 bf16x8 __attribute__((ext_vector_type(8)));
typedef float f32x4 __attribute__((ext_vector_type(4)));

#define T_SEQ 4096
#define C_DIM 1024
#define H_NUM 16
#define HD 64
#define C3 3072

__device__ __forceinline__ unsigned short f2bf(float f) {
    uint32_t u = __builtin_bit_cast(uint32_t, f);
    u += 0x7fffu + ((u >> 16) & 1u);
    return (unsigned short)(u >> 16);
}

__device__ __forceinline__ bf16x8 ld_bf8(const unsigned short* p) {
    return *reinterpret_cast<const bf16x8*>(p);
}

// ---- staging helpers: load 8 source elements -> 8 bf16 (16B) into LDS ----
__device__ __forceinline__ void stage8(const float* g, unsigned short* l) {
    float4 f0 = *(const float4*)g;
    float4 f1 = *(const float4*)(g + 4);
    union { unsigned short u[8]; uint4 q; } t;
    t.u[0] = f2bf(f0.x); t.u[1] = f2bf(f0.y); t.u[2] = f2bf(f0.z); t.u[3] = f2bf(f0.w);
    t.u[4] = f2bf(f1.x); t.u[5] = f2bf(f1.y); t.u[6] = f2bf(f1.z); t.u[7] = f2bf(f1.w);
    *(uint4*)l = t.q;
}
__device__ __forceinline__ void stage8(const unsigned short* g, unsigned short* l) {
    *(uint4*)l = *(const uint4*)g;
}

// ---- epilogue store: fp32 accumulator -> output element ----
__device__ __forceinline__ void store_c(unsigned short* C, size_t idx, float v) { C[idx] = f2bf(v); }
__device__ __forceinline__ void store_c(float* C, size_t idx, float v)          { C[idx] = v; }

// C = A @ B^T.  A: [M,K] row-major (TA). B: [N,K] row-major (TB). C: [M,N] (TC).
// 128x128 tile, BK=32, 4 waves in 2x2, each wave 64x64 (4x4 MFMA tiles).
// fp32 sources are converted to bf16 during LDS staging; compute is bf16 MFMA.
template <typename TA, typename TB, typename TC>
__global__ __launch_bounds__(256, 2) void gemm_bt(
    const TA* __restrict__ A, const TB* __restrict__ B,
    TC* __restrict__ C, int M, int N, int K)
{
    __shared__ __attribute__((aligned(16))) unsigned short As[128 * 32];
    __shared__ __attribute__((aligned(16))) unsigned short Bs[128 * 32];

    const int tid  = threadIdx.x;
    const int wave = tid >> 6, lane = tid & 63;
    const int quad = lane >> 4, l16 = lane & 15;
    const int wm = wave >> 1, wn = wave & 1;
    const int m0 = blockIdx.y * 128, n0 = blockIdx.x * 128;

    // staging map: lane -> (row = wave*32 + lane/4, 8-elem chunk = lane%4), x2 row-blocks
    const int srow = wave * 32 + (lane >> 2);
    const int scol = (lane & 3) * 8;

    f32x4 acc[4][4] = {};

    for (int k0 = 0; k0 < K; k0 += 32) {
        {
            const TA* ga = A + (size_t)(m0 + srow) * K + k0 + scol;
            const TB* gb = B + (size_t)(n0 + srow) * K + k0 + scol;
            stage8(ga,                  As + srow * 32 + scol);
            stage8(ga + (size_t)16 * K, As + (srow + 16) * 32 + scol);
            stage8(gb,                  Bs + srow * 32 + scol);
            stage8(gb + (size_t)16 * K, Bs + (srow + 16) * 32 + scol);
        }
        __syncthreads();

        bf16x8 af[4], bf[4];
        #pragma unroll
        for (int i = 0; i < 4; ++i) {
            af[i] = ld_bf8(As + (wm * 64 + i * 16 + l16) * 32 + quad * 8);
            bf[i] = ld_bf8(Bs + (wn * 64 + i * 16 + l16) * 32 + quad * 8);
        }
        #pragma unroll
        for (int mt = 0; mt < 4; ++mt)
            #pragma unroll
            for (int nt = 0; nt < 4; ++nt)
                acc[mt][nt] = __builtin_amdgcn_mfma_f32_16x16x32_bf16(
                    af[mt], bf[nt], acc[mt][nt], 0, 0, 0);
        __syncthreads();
    }

    #pragma unroll
    for (int mt = 0; mt < 4; ++mt)
        #pragma unroll
        for (int nt = 0; nt < 4; ++nt)
            #pragma unroll
            for (int r = 0; r < 4; ++r) {
                int row = m0 + wm * 64 + mt * 16 + quad * 4 + r;
                int col = n0 + wn * 64 + nt * 16 + l16;
                store_c(C, (size_t)row * N + col, acc[mt][nt][r]);
            }
}

// Flash attention, causal. qkv: [T, 3C] bf16 (q | k | v each C wide, head h at h*64).
// Block = (head, 64 q-rows), 4 waves each own a 16-row q-tile. Key tiles of 32.
#define NEG_BIG (-30000.0f)

__global__ __launch_bounds__(256, 2) void flash_attn(
    const unsigned short* __restrict__ qkv, unsigned short* __restrict__ Y)
{
    __shared__ __attribute__((aligned(16))) unsigned short Pl[4][16 * 32];

    const int tid  = threadIdx.x;
    const int wave = tid >> 6, lane = tid & 63;
    const int quad = lane >> 4, l16 = lane & 15;
    const int h  = blockIdx.y;
    const int qb = blockIdx.x;
    const int q0 = qb * 64 + wave * 16;

    // Q fragments (A-operand layout: m=l16, k=quad*8+j), hd=64 -> 2 K-chunks
    bf16x8 qf[2];
    {
        const unsigned short* qp = qkv + (size_t)(q0 + l16) * C3 + h * HD + quad * 8;
        qf[0] = ld_bf8(qp);
        qf[1] = ld_bf8(qp + 32);
    }

    f32x4 o[4] = {};          // O tile 16x64 in C-layout, 4 N-subtiles
    float m_r[4], l_r[4];
    #pragma unroll
    for (int r = 0; r < 4; ++r) { m_r[r] = NEG_BIG; l_r[r] = 0.f; }

    const int ktiles = (qb + 1) * 2;   // keys 0 .. qb*64+63, uniform across block
    for (int kt = 0; kt < ktiles; ++kt) {
        const int k0 = kt * 32;

        // S = Q K^T : two 16-col subtiles, 2 MFMAs each over hd=64
        f32x4 sa[2] = {};
        #pragma unroll
        for (int s = 0; s < 2; ++s) {
            const unsigned short* kp =
                qkv + (size_t)(k0 + s * 16 + l16) * C3 + C_DIM + h * HD + quad * 8;
            bf16x8 kf0 = ld_bf8(kp);
            bf16x8 kf1 = ld_bf8(kp + 32);
            sa[s] = __builtin_amdgcn_mfma_f32_16x16x32_bf16(qf[0], kf0, sa[s], 0, 0, 0);
            sa[s] = __builtin_amdgcn_mfma_f32_16x16x32_bf16(qf[1], kf1, sa[s], 0, 0, 0);
        }

        // scale + causal mask (C-layout: row=quad*4+r, col=l16)
        float sv[2][4];
        #pragma unroll
        for (int s = 0; s < 2; ++s)
            #pragma unroll
            for (int r = 0; r < 4; ++r) {
                int kc = k0 + s * 16 + l16;
                int qr = q0 + quad * 4 + r;
                float v = sa[s][r] * 0.125f;
                sv[s][r] = (kc <= qr) ? v : NEG_BIG;
            }

        // online softmax: row reductions live in 16-lane groups (same quad)
        #pragma unroll
        for (int r = 0; r < 4; ++r) {
            float tm = fmaxf(sv[0][r], sv[1][r]);
            #pragma unroll
            for (int off = 1; off < 16; off <<= 1)
                tm = fmaxf(tm, __shfl_xor(tm, off, 64));
            float mn    = fmaxf(m_r[r], tm);
            float alpha = __expf(m_r[r] - mn);     // arg in [-60000, 0]
            float p0 = __expf(sv[0][r] - mn);
            float p1 = __expf(sv[1][r] - mn);
            sv[0][r] = p0; sv[1][r] = p1;
            float ts = p0 + p1;
            #pragma unroll
            for (int off = 1; off < 16; off <<= 1)
                ts += __shfl_xor(ts, off, 64);
            m_r[r] = mn;
            l_r[r] = l_r[r] * alpha + ts;
            #pragma unroll
            for (int nt = 0; nt < 4; ++nt) o[nt][r] *= alpha;
        }

        // P: C-layout -> A-operand layout via LDS round trip (per-wave buffer)
        #pragma unroll
        for (int s = 0; s < 2; ++s)
            #pragma unroll
            for (int r = 0; r < 4; ++r)
                Pl[wave][(quad * 4 + r) * 32 + s * 16 + l16] = f2bf(sv[s][r]);
        __syncthreads();
        bf16x8 pf = ld_bf8(&Pl[wave][l16 * 32 + quad * 8]);

        // O += P V : B-operand layout n=l16 (channel), k=quad*8+j (key)
        #pragma unroll
        for (int nt = 0; nt < 4; ++nt) {
            union { unsigned short u[8]; bf16x8 v; } vf;
            #pragma unroll
            for (int j = 0; j < 8; ++j)
                vf.u[j] = qkv[(size_t)(k0 + quad * 8 + j) * C3 + 2 * C_DIM + h * HD + nt * 16 + l16];
            o[nt] = __builtin_amdgcn_mfma_f32_16x16x32_bf16(pf, vf.v, o[nt], 0, 0, 0);
        }
        __syncthreads();
    }

    // epilogue: normalize and write y [T, C] (bf16, feeds gemm2)
    #pragma unroll
    for (int nt = 0; nt < 4; ++nt)
        #pragma unroll
        for (int r = 0; r < 4; ++r) {
            int row = q0 + quad * 4 + r;
            int col = h * HD + nt * 16 + l16;
            Y[(size_t)row * C_DIM + col] = f2bf(o[nt][r] / l_r[r]);
        }
}

extern "C" void kernel_launch(void* const* d_in, const int* in_sizes, int n_in,
                              void* d_out, int out_size, void* d_ws, size_t ws_size,
                              hipStream_t stream) {
    const float* x      = (const float*)d_in[0];   // [4096, 1024] fp32
    const float* w_attn = (const float*)d_in[1];   // [3072, 1024] fp32
    const float* w_proj = (const float*)d_in[2];   // [1024, 1024] fp32
    float* out = (float*)d_out;                    // [4096, 1024] fp32

    unsigned short* qkv = (unsigned short*)d_ws;            // [4096, 3072] bf16
    unsigned short* y   = qkv + (size_t)T_SEQ * C3;         // [4096, 1024] bf16

    // qkv = bf16(x) @ bf16(w_attn)^T   (fp32 sources converted during staging)
    gemm_bt<float, float, unsigned short>
        <<<dim3(C3 / 128, T_SEQ / 128), 256, 0, stream>>>(x, w_attn, qkv, T_SEQ, C3, C_DIM);
    // y = attention(qkv)
    flash_attn<<<dim3(T_SEQ / 64, H_NUM), 256, 0, stream>>>(qkv, y);
    // out = y @ bf16(w_proj)^T  (fp32 output)
    gemm_bt<unsigned short, float, float>
        <<<dim3(C_DIM / 128, T_SEQ / 128), 256, 0, stream>>>(y, w_proj, out, T_SEQ, C_DIM, C_DIM);
}